// Round 3
// baseline (344.824 us; speedup 1.0000x reference)
//
#include <hip/hip_runtime.h>
#include <hip/hip_bf16.h>

#define BATCH 16
#define DIM   256
#define NH    8
#define CH    8
#define HH    56
#define WW    56
#define POS   3136          // 56*56
#define QKVC  192           // 3*DIM/DR
#define OC    64            // DIM/DR
#define SCALE 0.17677669529663687f   // 32^-0.5

// ---------------------------------------------------------------------------
// Kernel A: qkv = x @ qkv_w^T + qkv_b, stored as f[b][o][pos] fp32 (o<192)
// block 256 threads, 2 pixels/thread, o-tile 32. grid (7, 6, 16)
// ---------------------------------------------------------------------------
__global__ __launch_bounds__(256) void qkv_gemm(const float* __restrict__ x,
                                                const float* __restrict__ w,
                                                const float* __restrict__ bias,
                                                float* __restrict__ f) {
    __shared__ float wt[256][32];          // wt[c][o_local]
    const int tid = threadIdx.x;
    const int o0  = blockIdx.y * 32;
    const int b   = blockIdx.z;

    #pragma unroll
    for (int it = 0; it < 32; ++it) {      // 8192 weights
        int c = tid;                       // coalesced in c
        wt[c][it] = w[(o0 + it) * 256 + c];
    }
    __syncthreads();

    const int pos0 = blockIdx.x * 512 + tid;
    const int pos1 = pos0 + 256;
    const bool ok0 = pos0 < POS;
    const bool ok1 = pos1 < POS;

    float acc0[32], acc1[32];
    #pragma unroll
    for (int j = 0; j < 32; ++j) { acc0[j] = 0.f; acc1[j] = 0.f; }

    const float* xp = x + (size_t)b * DIM * POS;
    for (int c = 0; c < 256; ++c) {
        float xv0 = ok0 ? xp[c * POS + pos0] : 0.f;
        float xv1 = ok1 ? xp[c * POS + pos1] : 0.f;
        const float4* wr = (const float4*)&wt[c][0];
        #pragma unroll
        for (int j4 = 0; j4 < 8; ++j4) {
            float4 wv = wr[j4];
            acc0[j4*4+0] += xv0 * wv.x;  acc1[j4*4+0] += xv1 * wv.x;
            acc0[j4*4+1] += xv0 * wv.y;  acc1[j4*4+1] += xv1 * wv.y;
            acc0[j4*4+2] += xv0 * wv.z;  acc1[j4*4+2] += xv1 * wv.z;
            acc0[j4*4+3] += xv0 * wv.w;  acc1[j4*4+3] += xv1 * wv.w;
        }
    }

    float* fp = f + ((size_t)b * QKVC + o0) * POS;
    #pragma unroll
    for (int j = 0; j < 32; ++j) {
        float bj = bias[o0 + j];
        if (ok0) fp[j * POS + pos0] = acc0[j] + bj;
        if (ok1) fp[j * POS + pos1] = acc1[j] + bj;
    }
}

// ---------------------------------------------------------------------------
// Kernel B: slide attention. One block = (b, head, 8-row tile). 448 threads,
// one pixel each. k/v halo (10x58) x 8ch staged in LDS; weights packed
// wcp[ch][ka][12] = {w0..w8, kbias, vbias, pad} for float4 broadcast reads.
// grid (7, 8, 16)
// ---------------------------------------------------------------------------
#define TBH 8
__global__ __launch_bounds__(448) void attn_kernel(const float* __restrict__ f,
                                                   const float* __restrict__ dc_b,
                                                   const float* __restrict__ dc1_w,
                                                   const float* __restrict__ dc1_b,
                                                   const float* __restrict__ rpb,
                                                   float* __restrict__ aout) {
    __shared__ float kbuf[CH][TBH + 2][WW + 2];
    __shared__ float vbuf[CH][TBH + 2][WW + 2];
    __shared__ float wcp[CH * 9 * 12];

    const int tid = threadIdx.x;
    const int ty0 = blockIdx.x * TBH;
    const int h   = blockIdx.y;
    const int b   = blockIdx.z;
    const float* fb = f + ((size_t)b * QKVC + h * 24) * POS;

    // halo load: 16 channels (8 k then 8 v) x 10 rows x 58 cols
    const int HALO = (TBH + 2) * (WW + 2);   // 580
    for (int idx = tid; idx < 16 * HALO; idx += 448) {
        int c16 = idx / HALO;
        int rem = idx - c16 * HALO;
        int row = rem / (WW + 2);
        int col = rem - row * (WW + 2);
        int gy = ty0 + row - 1;
        int gx = col - 1;
        float val = 0.f;
        if (gy >= 0 && gy < HH && gx >= 0 && gx < WW) {
            int ch = c16 & 7;
            int o  = (c16 < 8) ? (8 + ch) : (16 + ch);
            val = fb[o * POS + gy * WW + gx];
        }
        float* dst = (c16 < 8) ? &kbuf[c16 & 7][0][0] : &vbuf[c16 & 7][0][0];
        dst[rem] = val;
    }
    // weights: 72 rows of 12
    for (int idx = tid; idx < 72; idx += 448) {
        int base = idx * 12;
        #pragma unroll
        for (int j = 0; j < 9; ++j) wcp[base + j] = dc1_w[idx * 9 + j];
        float db = dc_b[idx] + dc1_b[idx];
        int ka = idx % 9;
        wcp[base + 9]  = db + rpb[h * 9 + ka];   // k bias (+rpb)
        wcp[base + 10] = db;                     // v bias
        wcp[base + 11] = 0.f;
    }
    __syncthreads();

    const int ly  = tid / WW;            // 0..7 (448 = 8*56 exactly)
    const int lx  = tid - ly * WW;       // 0..55
    const int pos = (ty0 + ly) * WW + lx;

    float q[CH];
    #pragma unroll
    for (int ch = 0; ch < CH; ++ch) q[ch] = fb[ch * POS + pos] * SCALE;

    // ---- K pass: logits
    float logits[9];
    #pragma unroll
    for (int ka = 0; ka < 9; ++ka) logits[ka] = 0.f;
    #pragma unroll
    for (int ch = 0; ch < CH; ++ch) {
        float n[9];
        #pragma unroll
        for (int dy = 0; dy < 3; ++dy)
            #pragma unroll
            for (int dx = 0; dx < 3; ++dx)
                n[dy * 3 + dx] = kbuf[ch][ly + dy][lx + dx];
        float qc = q[ch];
        const float4* wp = (const float4*)&wcp[ch * 108];
        #pragma unroll
        for (int ka = 0; ka < 9; ++ka) {
            float4 a4 = wp[ka * 3 + 0];
            float4 b4 = wp[ka * 3 + 1];
            float4 c4 = wp[ka * 3 + 2];
            float kv = n[ka] + c4.y;
            kv += n[0]*a4.x + n[1]*a4.y + n[2]*a4.z + n[3]*a4.w;
            kv += n[4]*b4.x + n[5]*b4.y + n[6]*b4.z + n[7]*b4.w;
            kv += n[8]*c4.x;
            logits[ka] += qc * kv;
        }
    }

    // ---- softmax over 9
    float m = logits[0];
    #pragma unroll
    for (int ka = 1; ka < 9; ++ka) m = fmaxf(m, logits[ka]);
    float att[9];
    float s = 0.f;
    #pragma unroll
    for (int ka = 0; ka < 9; ++ka) { att[ka] = __expf(logits[ka] - m); s += att[ka]; }
    float inv = 1.f / s;
    #pragma unroll
    for (int ka = 0; ka < 9; ++ka) att[ka] *= inv;

    // ---- V pass: out[ch] = sum_ka att[ka] * v[ch][ka]
    float outv[CH];
    #pragma unroll
    for (int ch = 0; ch < CH; ++ch) {
        float n[9];
        #pragma unroll
        for (int dy = 0; dy < 3; ++dy)
            #pragma unroll
            for (int dx = 0; dx < 3; ++dx)
                n[dy * 3 + dx] = vbuf[ch][ly + dy][lx + dx];
        const float4* wp = (const float4*)&wcp[ch * 108];
        float o = 0.f;
        #pragma unroll
        for (int ka = 0; ka < 9; ++ka) {
            float4 a4 = wp[ka * 3 + 0];
            float4 b4 = wp[ka * 3 + 1];
            float4 c4 = wp[ka * 3 + 2];
            float vv = n[ka] + c4.z;
            vv += n[0]*a4.x + n[1]*a4.y + n[2]*a4.z + n[3]*a4.w;
            vv += n[4]*b4.x + n[5]*b4.y + n[6]*b4.z + n[7]*b4.w;
            vv += n[8]*c4.x;
            o += att[ka] * vv;
        }
        outv[ch] = o;
    }

    float* ap = aout + ((size_t)b * OC + h * CH) * POS + pos;
    #pragma unroll
    for (int ch = 0; ch < CH; ++ch) ap[ch * POS] = outv[ch];
}

// ---------------------------------------------------------------------------
// Kernel C: out = a @ proj_w^T + proj_b, fp32 NCHW output.
// block 256 threads, 2 pixels/thread, o-tile 32. grid (7, 8, 16)
// ---------------------------------------------------------------------------
__global__ __launch_bounds__(256) void proj_gemm(const float* __restrict__ a,
                                                 const float* __restrict__ w,
                                                 const float* __restrict__ bias,
                                                 float* __restrict__ out) {
    __shared__ float wt[64][32];           // wt[j][o_local]
    const int tid = threadIdx.x;
    const int o0  = blockIdx.y * 32;
    const int b   = blockIdx.z;

    #pragma unroll
    for (int it = 0; it < 8; ++it) {       // 2048 weights
        int idx = it * 256 + tid;
        int ol  = idx >> 6;                // 0..31
        int j   = idx & 63;                // coalesced in j
        wt[j][ol] = w[(o0 + ol) * 64 + j];
    }
    __syncthreads();

    const int pos0 = blockIdx.x * 512 + tid;
    const int pos1 = pos0 + 256;
    const bool ok0 = pos0 < POS;
    const bool ok1 = pos1 < POS;

    float acc0[32], acc1[32];
    #pragma unroll
    for (int j = 0; j < 32; ++j) { acc0[j] = 0.f; acc1[j] = 0.f; }

    const float* ap = a + (size_t)b * OC * POS;
    for (int j = 0; j < 64; ++j) {
        float a0 = ok0 ? ap[j * POS + pos0] : 0.f;
        float a1 = ok1 ? ap[j * POS + pos1] : 0.f;
        const float4* wr = (const float4*)&wt[j][0];
        #pragma unroll
        for (int j4 = 0; j4 < 8; ++j4) {
            float4 wv = wr[j4];
            acc0[j4*4+0] += a0 * wv.x;  acc1[j4*4+0] += a1 * wv.x;
            acc0[j4*4+1] += a0 * wv.y;  acc1[j4*4+1] += a1 * wv.y;
            acc0[j4*4+2] += a0 * wv.z;  acc1[j4*4+2] += a1 * wv.z;
            acc0[j4*4+3] += a0 * wv.w;  acc1[j4*4+3] += a1 * wv.w;
        }
    }

    float* op = out + ((size_t)b * DIM + o0) * POS;
    #pragma unroll
    for (int jl = 0; jl < 32; ++jl) {
        float bj = bias[o0 + jl];
        if (ok0) op[jl * POS + pos0] = acc0[jl] + bj;
        if (ok1) op[jl * POS + pos1] = acc1[jl] + bj;
    }
}

// ---------------------------------------------------------------------------
extern "C" void kernel_launch(void* const* d_in, const int* in_sizes, int n_in,
                              void* d_out, int out_size, void* d_ws, size_t ws_size,
                              hipStream_t stream) {
    const float* x      = (const float*)d_in[0];
    const float* qkv_w  = (const float*)d_in[1];
    const float* qkv_b  = (const float*)d_in[2];
    const float* dc_b   = (const float*)d_in[3];
    const float* dc1_w  = (const float*)d_in[4];
    const float* dc1_b  = (const float*)d_in[5];
    const float* rpb    = (const float*)d_in[6];
    const float* proj_w = (const float*)d_in[7];
    const float* proj_b = (const float*)d_in[8];
    float* out = (float*)d_out;

    // workspace: f (16*192*3136 fp32 = 38.5 MB) + a (16*64*3136 fp32 = 12.8 MB)
    float* f = (float*)d_ws;
    float* a = f + (size_t)BATCH * QKVC * POS;

    qkv_gemm<<<dim3(7, 6, BATCH), 256, 0, stream>>>(x, qkv_w, qkv_b, f);
    attn_kernel<<<dim3(7, NH, BATCH), 448, 0, stream>>>(f, dc_b, dc1_w, dc1_b, rpb, a);
    proj_gemm<<<dim3(7, 8, BATCH), 256, 0, stream>>>(a, proj_w, proj_b, out);
}